// Round 5
// baseline (238.110 us; speedup 1.0000x reference)
//
#include <hip/hip_runtime.h>

// LevelLayer fused single kernel with MANUAL grid barriers (no cooperative API
// — hipLaunchCooperativeKernel failed silently in R4; absmax matched the
// nothing-written stub). 256 blocks x 256 threads, 58.7 KB LDS -> 1 block/CU,
// all blocks co-resident on 256 CUs; barrier = agent-scope atomic arrival
// counter (zeroed via captured hipMemsetAsync), spin capped to avoid hangs.
// space_emb FFN -> kNN(k=15, per-event) -> 2x GIN(residual) -> out FFN
// N=8192 nodes = 32 events x 256. Block i owns nodes [32i, 32i+32).
// 2 device-wide syncs: after space (pos/hA), after gin1 (hB). knn block i
// produces exactly gin block i's nbr rows; gin2 out range == out_emb in range.
// Input float dtype runtime-detected (bf16 vs fp32) inline; outputs stored per
// same flag. d_out: h[8192*64] | x_emb[8192*4] | ei[2*122880].

#define N_NODES 8192
#define NPE     256
#define KNN     15
#define LAT     64
#define HID     128
#define NK      (N_NODES*KNN)
#define NBLK    256

typedef unsigned short bf16;
typedef unsigned int   u32;
typedef unsigned long long u64;

__device__ __forceinline__ float bf2f(bf16 s) {
    union { u32 u; float f; } v; v.u = ((u32)s) << 16; return v.f;
}
__device__ __forceinline__ bf16 f2bf(float f) {
    union { float f; u32 u; } v; v.f = f;
    u32 u = v.u + 0x7fffu + ((v.u >> 16) & 1u);   // RNE
    return (bf16)(u >> 16);
}

struct Params {
    const void *x, *se1, *bse1, *se2, *bse2,
               *g1a, *bg1a, *g1b, *bg1b, *g2a, *bg2a, *g2b, *bg2b,
               *oe1, *boe1, *oe2, *boe2;
    float *hA, *hB, *pos; int* nbr; int* bar; void* out;
};

union __align__(16) SMem {
    struct { float xv[128]; float W1[4*LAT]; float W2[LAT*LAT];
             float b1[LAT]; float b2[LAT]; float hid[4][LAT]; } sp;      // ~19.3 KB
    struct { float pos[NPE*3]; } kn;                                     // 3 KB
    struct { float W[LAT*HID]; float m[32*LAT]; float t[32*HID];
             float ba[HID]; float bb[LAT]; int nb[32*KNN]; } gi;         // ~58.7 KB
    struct { float W1[LAT*LAT]; float W2[LAT*4]; float b1[LAT];
             float b2[4]; float h[4][LAT]; float t[4][LAT]; } ou;        // ~19.5 KB
};

// device-wide barrier: one fresh counter per use (zeroed before launch).
// release: prior global writes visible via threadfence + ACQ_REL RMW;
// acquire: spin-load pairs with other blocks' release. Spin capped: a
// co-residency failure gives a wrong answer, not a harness hang.
__device__ __forceinline__ void grid_barrier(int* cnt) {
    __syncthreads();
    if (threadIdx.x == 0) {
        __threadfence();
        __hip_atomic_fetch_add(cnt, 1, __ATOMIC_ACQ_REL, __HIP_MEMORY_SCOPE_AGENT);
        for (long i = 0; i < 200000000L; i++) {
            if (__hip_atomic_load(cnt, __ATOMIC_ACQUIRE, __HIP_MEMORY_SCOPE_AGENT) >= NBLK)
                break;
            __builtin_amdgcn_s_sleep(1);
        }
    }
    __syncthreads();
}

// explicit uniform branch (NOT a ternary) so no speculative OOB load of the
// wrong-dtype interpretation can be emitted.
__device__ __forceinline__ void stage(float* dst, const void* src, int n, bool f32, int tid) {
    if (f32) { const float* s = (const float*)src; for (int i = tid; i < n; i += 256) dst[i] = s[i]; }
    else     { const bf16* s = (const bf16*)src;  for (int i = tid; i < n; i += 256) dst[i] = bf2f(s[i]); }
}

__device__ __forceinline__ void gin_block(SMem& s, const float* __restrict__ hin,
    float* __restrict__ hout, const int* __restrict__ nbr,
    const void* Wa, const void* ba, const void* Wb, const void* bb,
    bool f32, int blk, int tid)
{
    const int base = blk * 32;
    for (int i = tid; i < 32 * KNN; i += 256) s.gi.nb[i] = nbr[base * KNN + i] & (N_NODES - 1);
    stage(s.gi.W,  Wa, LAT * HID, f32, tid);
    stage(s.gi.ba, ba, HID,       f32, tid);
    stage(s.gi.bb, bb, LAT,       f32, tid);
    __syncthreads();
    // phase 1: m = own + sum of 15 neighbors, 32 nodes x 64 f
    #pragma unroll
    for (int ph = 0; ph < 8; ph++) {
        const int e = tid + ph * 256, n = e >> 6, f = e & 63, gi = base + n;
        float acc = hin[gi * LAT + f];
        #pragma unroll
        for (int k = 0; k < KNN; k++) acc += hin[s.gi.nb[n * KNN + k] * LAT + f];
        s.gi.m[e] = acc;
    }
    __syncthreads();
    // phase 2: t = relu(m @ Wa + ba); 4 chunks of 8 nodes
    #pragma unroll
    for (int c = 0; c < 4; c++) {
        const int n = c * 8 + (tid >> 5), ug = (tid & 31) * 4;
        float a0 = s.gi.ba[ug], a1 = s.gi.ba[ug+1], a2 = s.gi.ba[ug+2], a3 = s.gi.ba[ug+3];
        for (int f = 0; f < LAT; f++) {
            const float mv = s.gi.m[n * LAT + f];
            const float4 w = *(const float4*)&s.gi.W[f * HID + ug];
            a0 = fmaf(mv, w.x, a0); a1 = fmaf(mv, w.y, a1);
            a2 = fmaf(mv, w.z, a2); a3 = fmaf(mv, w.w, a3);
        }
        float4 r;
        r.x = a0 > 0.f ? a0 : 0.f; r.y = a1 > 0.f ? a1 : 0.f;
        r.z = a2 > 0.f ? a2 : 0.f; r.w = a3 > 0.f ? a3 : 0.f;
        *(float4*)&s.gi.t[n * HID + ug] = r;
    }
    __syncthreads();
    stage(s.gi.W, Wb, HID * LAT, f32, tid);   // re-stage slab with Wb
    __syncthreads();
    // phase 3: g = t @ Wb + bb; hout = own(global re-read) + g
    #pragma unroll
    for (int c = 0; c < 4; c++) {
        const int n = c * 8 + (tid >> 5), fp = (tid & 31) * 2, gi = base + n;
        float a0 = s.gi.bb[fp], a1 = s.gi.bb[fp + 1];
        for (int u = 0; u < HID; u++) {
            const float tv = s.gi.t[n * HID + u];
            const float2 w = *(const float2*)&s.gi.W[u * LAT + fp];
            a0 = fmaf(tv, w.x, a0); a1 = fmaf(tv, w.y, a1);
        }
        float2 o;
        o.x = hin[gi * LAT + fp]     + a0;
        o.y = hin[gi * LAT + fp + 1] + a1;
        *(float2*)&hout[gi * LAT + fp] = o;
    }
}

__global__ __launch_bounds__(256) void k_fused(Params p)
{
    __shared__ SMem s;
    const int tid = threadIdx.x, blk = blockIdx.x;

    // ---- inline dtype detect: all threads scan same 128 words (uniform) ----
    int cnt = 0;
    const u32* wdet = (const u32*)p.g1a;
    #pragma unroll 8
    for (int i = 0; i < 128; i++) {
        const u32 v = wdet[i];
        cnt += ((v >> 7)  & 0xffu) >= 0xC8u;   // low half as bf16 exp
        cnt += ((v >> 23) & 0xffu) >= 0xC8u;   // high half as bf16 exp
    }
    const bool f32 = cnt > 8;                   // fp32 mantissa bits trip this ~22%/word

    // ================= Phase A: space_emb for nodes [32*blk, +32) ==========
    {
        stage(s.sp.xv, f32 ? (const void*)((const float*)p.x + blk * 128)
                           : (const void*)((const bf16*)p.x + blk * 128), 128, f32, tid);
        stage(s.sp.W1, p.se1, 4 * LAT,   f32, tid);
        stage(s.sp.W2, p.se2, LAT * LAT, f32, tid);
        stage(s.sp.b1, p.bse1, LAT, f32, tid);
        stage(s.sp.b2, p.bse2, LAT, f32, tid);
        __syncthreads();
        const int ln = tid >> 6, f = tid & 63;
        for (int g = 0; g < 8; g++) {
            const int node = blk * 32 + g * 4 + ln;
            float acc = s.sp.b1[f];
            #pragma unroll
            for (int i = 0; i < 4; i++)
                acc = fmaf(s.sp.xv[(g * 4 + ln) * 4 + i], s.sp.W1[i * LAT + f], acc);
            acc = acc > 0.f ? acc : 0.01f * acc;          // leaky
            s.sp.hid[ln][f] = acc;
            __syncthreads();
            float a2 = s.sp.b2[f];
            #pragma unroll
            for (int j = 0; j < LAT; j++) a2 = fmaf(s.sp.hid[ln][j], s.sp.W2[j * LAT + f], a2);
            p.hA[node * LAT + f] = a2;
            if (f < 3) p.pos[node * 3 + f] = a2;
            __syncthreads();
        }
    }
    grid_barrier(p.bar + 0);                     // pos + hA visible device-wide

    // ================= Phase B: kNN for nodes [32*blk, +32) ================
    {
        const int sub = blk & 7, eb = (blk >> 3) * NPE;
        for (int i = tid; i < NPE * 3; i += 256) s.kn.pos[i] = p.pos[eb * 3 + i];
        __syncthreads();
        const int wave = tid >> 6, lane = tid & 63;
        const int EI0 = N_NODES * LAT + N_NODES * 4;
        for (int r = 0; r < 8; r++) {
            const int nl = sub * 32 + wave * 8 + r;
            const int n  = eb + nl;
            const float px = s.kn.pos[nl*3], py = s.kn.pos[nl*3+1], pz = s.kn.pos[nl*3+2];
            u64 key[4];
            #pragma unroll
            for (int c = 0; c < 4; c++) {
                const int j = 64 * c + lane;
                const float dx = px - s.kn.pos[j*3], dy = py - s.kn.pos[j*3+1], dz = pz - s.kn.pos[j*3+2];
                float dd = __fmul_rn(dx, dx);                 // match np fp32 order
                dd = __fadd_rn(dd, __fmul_rn(dy, dy));
                dd = __fadd_rn(dd, __fmul_rn(dz, dz));
                key[c] = ((u64)__float_as_uint(dd) << 32) | (u32)j;
                if (j == nl) key[c] = ~0ull;                  // exclude self
            }
            u64 lmin = key[0] < key[1] ? key[0] : key[1];
            { u64 t = key[2] < key[3] ? key[2] : key[3]; lmin = t < lmin ? t : lmin; }
            int myj = 0;                                      // lane k holds k-th winner
            #pragma unroll
            for (int k = 0; k < KNN; k++) {
                u64 m = lmin;
                #pragma unroll
                for (int sft = 32; sft >= 1; sft >>= 1) {
                    const u64 o = __shfl_xor(m, sft, 64);
                    m = o < m ? o : m;
                }
                if (lane == k) myj = (int)(u32)m;
                #pragma unroll
                for (int c = 0; c < 4; c++) if (key[c] == m) key[c] = ~0ull;
                lmin = key[0] < key[1] ? key[0] : key[1];
                { u64 t = key[2] < key[3] ? key[2] : key[3]; lmin = t < lmin ? t : lmin; }
            }
            if (lane < KNN) {
                const int gj = eb + myj;
                p.nbr[n * KNN + lane] = gj;
                if (f32) {
                    float* o = (float*)p.out;
                    o[EI0 + n * KNN + lane]      = (float)gj;
                    o[EI0 + NK + n * KNN + lane] = (float)n;
                } else {
                    bf16* o = (bf16*)p.out;
                    o[EI0 + n * KNN + lane]      = f2bf((float)gj);
                    o[EI0 + NK + n * KNN + lane] = f2bf((float)n);
                }
            }
        }
        __syncthreads();   // nbr (this block's rows) written; LDS about to be reused
    }

    // ================= Phase C: GIN1 hA -> hB (block-local nbr) ============
    gin_block(s, p.hA, p.hB, p.nbr, p.g1a, p.bg1a, p.g1b, p.bg1b, f32, blk, tid);
    grid_barrier(p.bar + 16);                    // hB visible device-wide

    // ================= Phase D: GIN2 hB -> hA ==============================
    gin_block(s, p.hB, p.hA, p.nbr, p.g2a, p.bg2a, p.g2b, p.bg2b, f32, blk, tid);
    __syncthreads();                             // block-local: D out == E in range

    // ================= Phase E: out_emb + final stores =====================
    {
        stage(s.ou.W1, p.oe1, LAT * LAT, f32, tid);
        stage(s.ou.W2, p.oe2, LAT * 4,  f32, tid);
        stage(s.ou.b1, p.boe1, LAT, f32, tid);
        stage(s.ou.b2, p.boe2, 4,   f32, tid);
        __syncthreads();
        const int ln = tid >> 6, f = tid & 63;
        for (int g = 0; g < 8; g++) {
            const int node = blk * 32 + g * 4 + ln;
            const float hv = p.hA[node * LAT + f];
            s.ou.h[ln][f] = hv;
            if (f32) ((float*)p.out)[node * LAT + f] = hv;          // output 0: h
            else     ((bf16*)p.out)[node * LAT + f] = f2bf(hv);
            __syncthreads();
            float acc = s.ou.b1[f];
            #pragma unroll
            for (int j = 0; j < LAT; j++) acc = fmaf(s.ou.h[ln][j], s.ou.W1[j * LAT + f], acc);
            acc = acc > 0.f ? acc : 0.01f * acc;                    // leaky
            s.ou.t[ln][f] = acc;
            __syncthreads();
            if (f < 4) {
                float a = s.ou.b2[f];
                #pragma unroll
                for (int j = 0; j < LAT; j++) a = fmaf(s.ou.t[ln][j], s.ou.W2[j * 4 + f], a);
                const int xo = N_NODES * LAT + node * 4 + f;        // output 1: x_emb
                if (f32) ((float*)p.out)[xo] = a;
                else     ((bf16*)p.out)[xo] = f2bf(a);
            }
            __syncthreads();
        }
    }
}

extern "C" void kernel_launch(void* const* d_in, const int* in_sizes, int n_in,
                              void* d_out, int out_size, void* d_ws, size_t ws_size,
                              hipStream_t stream)
{
    (void)in_sizes; (void)n_in; (void)out_size; (void)ws_size;
    char* ws = (char*)d_ws;
    Params p;
    p.x   = d_in[0];
    p.se1 = d_in[3];  p.bse1 = d_in[4];
    p.se2 = d_in[5];  p.bse2 = d_in[6];
    p.g1a = d_in[7];  p.bg1a = d_in[8];
    p.g1b = d_in[9];  p.bg1b = d_in[10];
    p.g2a = d_in[11]; p.bg2a = d_in[12];
    p.g2b = d_in[13]; p.bg2b = d_in[14];
    p.oe1 = d_in[15]; p.boe1 = d_in[16];
    p.oe2 = d_in[17]; p.boe2 = d_in[18];
    p.bar = (int*)ws;                                     // 2 counters, 256 B
    p.hA  = (float*)(ws + 256);                           // 2 MB
    p.hB  = (float*)(ws + 256 + 2097152);                 // 2 MB
    p.pos = (float*)(ws + 256 + 4194304);                 // 96 KB
    p.nbr = (int*)(ws + 256 + 4194304 + 131072);          // 480 KB
    p.out = d_out;

    hipMemsetAsync(ws, 0, 256, stream);                   // zero barrier counters
    k_fused<<<NBLK, 256, 0, stream>>>(p);
}